// Round 14
// baseline (1056.930 us; speedup 1.0000x reference)
//
#include <hip/hip_runtime.h>
#include <hip/hip_fp16.h>

#define NN 50000
#define NE 1200000
#define DIM 64
#define NB 782            // node buckets of 64: ceil(50000/64)
#define BB 196            // ceil(NB/4)
#define SLICES 256
#define ES 4688           // ceil(NE/SLICES)
#define VCAP 2048         // vsort bucket cache cap (mean 1536, ~13 sigma)
#define GB 782            // tile blocks: ceil(NN/64)

// ---------------- slice bucket-sort
__global__ __launch_bounds__(256) void k_lsort(const int* __restrict__ ei,
                                               ushort* __restrict__ usort,
                                               int* __restrict__ ebuf,
                                               int* __restrict__ lpart_u,
                                               int* __restrict__ lpart_v) {
    __shared__ int hist[NB + 1];
    __shared__ int scratch[256];
    __shared__ int sb[ES];          // union: U pass uses as ushort[], V as int[]
    ushort* sbu = (ushort*)sb;
    int t = threadIdx.x, s = blockIdx.x;
    int e0 = s * ES, e1 = min(e0 + ES, NE), len = e1 - e0;
    int i0 = t * 4;

    // ======== pass U
    for (int i = t; i < NB; i += 256) hist[i] = 0;
    __syncthreads();
    for (int e = e0 + t; e < e1; e += 256) atomicAdd(&hist[ei[e] >> 6], 1);
    __syncthreads();
    {
        int h0 = (i0 + 0 < NB) ? hist[i0 + 0] : 0;
        int h1 = (i0 + 1 < NB) ? hist[i0 + 1] : 0;
        int h2 = (i0 + 2 < NB) ? hist[i0 + 2] : 0;
        int h3 = (i0 + 3 < NB) ? hist[i0 + 3] : 0;
        int p1 = h0, p2 = h0 + h1, p3 = p2 + h2, p4 = p3 + h3;
        scratch[t] = p4;
        __syncthreads();
        for (int off = 1; off < 256; off <<= 1) {
            int x = 0;
            if (t >= off) x = scratch[t - off];
            __syncthreads();
            scratch[t] += x;
            __syncthreads();
        }
        int excl = scratch[t] - p4;
        int* lpu = lpart_u + s * (NB + 1);
        if (i0 + 0 < NB) { lpu[i0 + 0] = excl;      hist[i0 + 0] = excl; }
        if (i0 + 1 < NB) { lpu[i0 + 1] = excl + p1; hist[i0 + 1] = excl + p1; }
        if (i0 + 2 < NB) { lpu[i0 + 2] = excl + p2; hist[i0 + 2] = excl + p2; }
        if (i0 + 3 < NB) { lpu[i0 + 3] = excl + p3; hist[i0 + 3] = excl + p3; }
        if (t == 255) lpu[NB] = scratch[255];
    }
    __syncthreads();
    for (int e = e0 + t; e < e1; e += 256) {
        int u = ei[e];
        int pos = atomicAdd(&hist[u >> 6], 1);
        sbu[pos] = (ushort)u;
    }
    __syncthreads();
    for (int i = t; i < len; i += 256) usort[e0 + i] = sbu[i];
    __syncthreads();

    // ======== pass V
    for (int i = t; i < NB; i += 256) hist[i] = 0;
    __syncthreads();
    for (int e = e0 + t; e < e1; e += 256) atomicAdd(&hist[ei[NE + e] >> 6], 1);
    __syncthreads();
    {
        int h0 = (i0 + 0 < NB) ? hist[i0 + 0] : 0;
        int h1 = (i0 + 1 < NB) ? hist[i0 + 1] : 0;
        int h2 = (i0 + 2 < NB) ? hist[i0 + 2] : 0;
        int h3 = (i0 + 3 < NB) ? hist[i0 + 3] : 0;
        int p1 = h0, p2 = h0 + h1, p3 = p2 + h2, p4 = p3 + h3;
        scratch[t] = p4;
        __syncthreads();
        for (int off = 1; off < 256; off <<= 1) {
            int x = 0;
            if (t >= off) x = scratch[t - off];
            __syncthreads();
            scratch[t] += x;
            __syncthreads();
        }
        int excl = scratch[t] - p4;
        int* lpv = lpart_v + s * (NB + 1);
        if (i0 + 0 < NB) { lpv[i0 + 0] = excl;      hist[i0 + 0] = excl; }
        if (i0 + 1 < NB) { lpv[i0 + 1] = excl + p1; hist[i0 + 1] = excl + p1; }
        if (i0 + 2 < NB) { lpv[i0 + 2] = excl + p2; hist[i0 + 2] = excl + p2; }
        if (i0 + 3 < NB) { lpv[i0 + 3] = excl + p3; hist[i0 + 3] = excl + p3; }
        if (t == 255) lpv[NB] = scratch[255];
    }
    __syncthreads();
    for (int e = e0 + t; e < e1; e += 256) {
        int u = ei[e], v = ei[NE + e];
        int pos = atomicAdd(&hist[v >> 6], 1);
        sb[pos] = u | ((v & 63) << 16);
    }
    __syncthreads();
    for (int i = t; i < len; i += 256) ebuf[e0 + i] = sb[i];
}

// ---------------- GEMM (fp32 math): Ch = half(A@W + b)  (layer-0 encoder)
__global__ __launch_bounds__(256) void k_gemm_h(const float* __restrict__ A,
                                                const float* __restrict__ W,
                                                const float* __restrict__ bias,
                                                __half* __restrict__ Ch, int M) {
    __shared__ float As[64][68];
    __shared__ float Bs[64][64];
    int t = threadIdx.x;
    int row0 = blockIdx.x * 64;
#pragma unroll
    for (int i = 0; i < 4; ++i) {
        int idx = t + i * 256;
        int r = idx >> 4, c = (idx & 15) << 2;
        float4 val = make_float4(0.f, 0.f, 0.f, 0.f);
        if (row0 + r < M) val = *(const float4*)&A[(size_t)(row0 + r) * DIM + c];
        *(float4*)&As[r][c] = val;
        *(float4*)&Bs[r][c] = *(const float4*)&W[r * DIM + c];
    }
    __syncthreads();
    int r0 = (t >> 4) * 4;
    int c0 = (t & 15) * 4;
    float acc[4][4] = {};
#pragma unroll
    for (int k = 0; k < 64; k += 4) {
        float4 b0 = *(float4*)&Bs[k + 0][c0];
        float4 b1 = *(float4*)&Bs[k + 1][c0];
        float4 b2 = *(float4*)&Bs[k + 2][c0];
        float4 b3 = *(float4*)&Bs[k + 3][c0];
#pragma unroll
        for (int i = 0; i < 4; ++i) {
            float4 av = *(float4*)&As[r0 + i][k];
            acc[i][0] = fmaf(av.x, b0.x, fmaf(av.y, b1.x, fmaf(av.z, b2.x, fmaf(av.w, b3.x, acc[i][0]))));
            acc[i][1] = fmaf(av.x, b0.y, fmaf(av.y, b1.y, fmaf(av.z, b2.y, fmaf(av.w, b3.y, acc[i][1]))));
            acc[i][2] = fmaf(av.x, b0.z, fmaf(av.y, b1.z, fmaf(av.z, b2.z, fmaf(av.w, b3.z, acc[i][2]))));
            acc[i][3] = fmaf(av.x, b0.w, fmaf(av.y, b1.w, fmaf(av.z, b2.w, fmaf(av.w, b3.w, acc[i][3]))));
        }
    }
    float4 bv = *(const float4*)&bias[c0];
#pragma unroll
    for (int i = 0; i < 4; ++i) {
        int r = row0 + r0 + i;
        if (r < M) {
            __half2 p0 = __floats2half2_rn(acc[i][0] + bv.x, acc[i][1] + bv.y);
            __half2 p1 = __floats2half2_rn(acc[i][2] + bv.z, acc[i][3] + bv.w);
            uint2 pk;
            pk.x = *(unsigned int*)&p0;
            pk.y = *(unsigned int*)&p1;
            *(uint2*)&Ch[(size_t)r * DIM + c0] = pk;
        }
    }
}

// ---------------- fused: [0,BB) u-count -> dis; [BB,2*BB) v-bucket totals.
// Block 0 zeroes colsum + done counter.
__global__ __launch_bounds__(256) void k_mid(const ushort* __restrict__ usort,
                                             const int* __restrict__ lpart_u,
                                             const int* __restrict__ lpart_v,
                                             float* __restrict__ dis,
                                             int* __restrict__ tot,
                                             float* __restrict__ colsum,
                                             int* __restrict__ done) {
    __shared__ int sh[4][64];
    int bid = blockIdx.x;
    if (bid == 0) {
        if (threadIdx.x < 64) colsum[threadIdx.x] = 0.f;
        if (threadIdx.x == 64) *done = 0;
    }
    int w = threadIdx.x >> 6, l = threadIdx.x & 63;
    if (bid < BB) {
        int b = bid * 4 + w;
        if (b >= NB) return;
        sh[w][l] = 0;
        __builtin_amdgcn_wave_barrier();
        for (int s = l; s < SLICES; s += 64) {
            const int* row = lpart_u + s * (NB + 1);
            int st = row[b], en = row[b + 1];
            for (int i = st; i < en; ++i)
                atomicAdd(&sh[w][usort[s * ES + i] & 63], 1);
        }
        __builtin_amdgcn_wave_barrier();
        int n = (b << 6) + l;
        if (n < NN) dis[n] = rsqrtf((float)sh[w][l] + 1.0f);
    } else {
        int c = (bid - BB) * 4 + w;
        if (c >= NB) return;
        int sum = 0;
        for (int s = l; s < SLICES; s += 64) {
            const int* row = lpart_v + s * (NB + 1);
            sum += row[c + 1] - row[c];
        }
        for (int off = 32; off; off >>= 1) sum += __shfl_down(sum, off, 64);
        if (l == 0) tot[c] = sum;
    }
}

// ---------------- per-bucket counting sort, LDS-cached; base_v self-computed.
__global__ __launch_bounds__(256) void k_vsort(const int* __restrict__ ebuf,
                                               const int* __restrict__ lpart_v,
                                               const int* __restrict__ tot,
                                               const float* __restrict__ dis,
                                               int* __restrict__ edges,
                                               int* __restrict__ row_ptr) {
    __shared__ int cache[4][VCAP];
    __shared__ int cnt[4][64];
    __shared__ int cur[4][64];
    int w = threadIdx.x >> 6, l = threadIdx.x & 63;
    int b = blockIdx.x * 4 + w;
    if (b >= NB) return;
    int partial = 0;
    for (int c = l; c < b; c += 64) partial += tot[c];
    for (int off = 32; off; off >>= 1) partial += __shfl_down(partial, off, 64);
    int rbase = __shfl(partial, 0, 64);
    int n = tot[b];
    cnt[w][l] = 0;
    __builtin_amdgcn_wave_barrier();
    if (n <= VCAP) {
        int len[4]; int tl = 0;
#pragma unroll
        for (int k = 0; k < 4; ++k) {
            const int* row = lpart_v + (l * 4 + k) * (NB + 1);
            len[k] = row[b + 1] - row[b];
            tl += len[k];
        }
        int inc = tl;
        for (int o = 1; o < 64; o <<= 1) {
            int x = __shfl_up(inc, o, 64);
            if (l >= o) inc += x;
        }
        int pos = inc - tl;
#pragma unroll
        for (int k = 0; k < 4; ++k) {
            int s = l * 4 + k;
            const int* row = lpart_v + s * (NB + 1);
            int st = row[b];
            for (int i = 0; i < len[k]; ++i)
                cache[w][pos++] = ebuf[s * ES + st + i];
        }
        __builtin_amdgcn_wave_barrier();
        for (int i = l; i < n; i += 64)
            atomicAdd(&cnt[w][(cache[w][i] >> 16) & 63], 1);
        __builtin_amdgcn_wave_barrier();
        int c = cnt[w][l];
        int inc2 = c;
        for (int o = 1; o < 64; o <<= 1) {
            int x = __shfl_up(inc2, o, 64);
            if (l >= o) inc2 += x;
        }
        int excl = inc2 - c;
        cur[w][l] = rbase + excl;
        row_ptr[(b << 6) + l] = rbase + excl;
        __builtin_amdgcn_wave_barrier();
        for (int i = l; i < n; i += 64) {
            int rec = cache[w][i];
            int u = rec & 0xFFFF;
            int p2 = atomicAdd(&cur[w][(rec >> 16) & 63], 1);
            ushort dh = __half_as_ushort(__float2half_rn(dis[u]));
            edges[p2] = u | ((int)dh << 16);
        }
    } else {
        for (int s = l; s < SLICES; s += 64) {
            const int* row = lpart_v + s * (NB + 1);
            int st = row[b], en = row[b + 1];
            for (int i = st; i < en; ++i)
                atomicAdd(&cnt[w][(ebuf[s * ES + i] >> 16) & 63], 1);
        }
        __builtin_amdgcn_wave_barrier();
        int c = cnt[w][l];
        int inc2 = c;
        for (int o = 1; o < 64; o <<= 1) {
            int x = __shfl_up(inc2, o, 64);
            if (l >= o) inc2 += x;
        }
        int excl = inc2 - c;
        cur[w][l] = rbase + excl;
        row_ptr[(b << 6) + l] = rbase + excl;
        __builtin_amdgcn_wave_barrier();
        for (int s = l; s < SLICES; s += 64) {
            const int* row = lpart_v + s * (NB + 1);
            int st = row[b], en = row[b + 1];
            for (int i = st; i < en; ++i) {
                int rec = ebuf[s * ES + i];
                int u = rec & 0xFFFF;
                int p2 = atomicAdd(&cur[w][(rec >> 16) & 63], 1);
                ushort dh = __half_as_ushort(__float2half_rn(dis[u]));
                edges[p2] = u | ((int)dh << 16);
            }
        }
    }
}

// ================= fused layer (agg tile -> LDS, then GEMM). VGPR-capped.
__device__ __forceinline__ void agg_tile(float (*As)[68], int (*se)[64],
                                         const uint2* __restrict__ Hq,
                                         const float* __restrict__ dis,
                                         const int* __restrict__ row_ptr,
                                         const int* __restrict__ edges,
                                         int n0) {
    int w = threadIdx.x >> 6, l = threadIdx.x & 63;
    int g = l >> 4, p = l & 15;
    for (int i = 0; i < 16; ++i) {
        int row = (w << 4) + i;
        int node = n0 + row;
        if (node < NN) {                      // wave-uniform branch
            int start = row_ptr[node];
            int num = row_ptr[node + 1] - start;
            float4 acc = {0.f, 0.f, 0.f, 0.f};
            for (int base = 0; base < num; base += 64) {
                int lim = min(64, num - base);
                se[w][l] = (l < lim) ? edges[start + base + l] : 0;
                __builtin_amdgcn_wave_barrier();
                int quads = (lim + 3) >> 2;
                for (int j = 0; j < quads; j += 8) {
                    int rr[8]; uint2 hh[8];
#pragma unroll
                    for (int q = 0; q < 8; ++q) rr[q] = se[w][4 * (j + q) + g];
#pragma unroll
                    for (int q = 0; q < 8; ++q) hh[q] = Hq[((rr[q] & 0xFFFF) << 4) + p];
#pragma unroll
                    for (int q = 0; q < 8; ++q) {
                        float wt = __half2float(__ushort_as_half((ushort)((unsigned)rr[q] >> 16)));
                        float2 f0 = __half22float2(*(const __half2*)&hh[q].x);
                        float2 f1 = __half22float2(*(const __half2*)&hh[q].y);
                        acc.x = fmaf(wt, f0.x, acc.x);
                        acc.y = fmaf(wt, f0.y, acc.y);
                        acc.z = fmaf(wt, f1.x, acc.z);
                        acc.w = fmaf(wt, f1.y, acc.w);
                    }
                }
                __builtin_amdgcn_wave_barrier();
            }
#pragma unroll
            for (int m = 16; m < 64; m <<= 1) {
                acc.x += __shfl_xor(acc.x, m, 64);
                acc.y += __shfl_xor(acc.y, m, 64);
                acc.z += __shfl_xor(acc.z, m, 64);
                acc.w += __shfl_xor(acc.w, m, 64);
            }
            if (g == 0) {
                uint2 sv = Hq[(node << 4) + p];
                float2 s0 = __half22float2(*(const __half2*)&sv.x);
                float2 s1 = __half22float2(*(const __half2*)&sv.y);
                float dv = dis[node];
                float4 o;
                o.x = fmaf(dv, acc.x, s0.x);
                o.y = fmaf(dv, acc.y, s0.y);
                o.z = fmaf(dv, acc.z, s1.x);
                o.w = fmaf(dv, acc.w, s1.y);
                *(float4*)&As[row][p << 2] = o;
            }
        } else {
            if (g == 0) *(float4*)&As[row][p << 2] = make_float4(0.f, 0.f, 0.f, 0.f);
        }
    }
}

// layers 0/1: Zh = half(relu(X@W1+b1)@W2 + b2), X = aggregated tile.
// __launch_bounds__(256,4): cap VGPR at 128 so all ~12 waves/CU stay resident
// (R13's unbounded build hit 244 VGPR -> 8.5% occupancy -> 130 us).
__global__ __launch_bounds__(256, 4) void k_layer(const uint2* __restrict__ Hq,
                                                  const float* __restrict__ dis,
                                                  const int* __restrict__ row_ptr,
                                                  const int* __restrict__ edges,
                                                  const float* __restrict__ W1,
                                                  const float* __restrict__ b1,
                                                  const float* __restrict__ W2,
                                                  const float* __restrict__ b2,
                                                  __half* __restrict__ Zh) {
    __shared__ float As[64][68];
    __shared__ float Bs[64][64];
    __shared__ int se[4][64];
    int t = threadIdx.x;
    int n0 = blockIdx.x * 64;

    agg_tile(As, se, Hq, dis, row_ptr, edges, n0);
    __syncthreads();

#pragma unroll
    for (int i = 0; i < 4; ++i) {
        int idx = t + i * 256;
        int r = idx >> 4, c = (idx & 15) << 2;
        *(float4*)&Bs[r][c] = *(const float4*)&W1[r * DIM + c];
    }
    __syncthreads();
    int r0 = (t >> 4) * 4;
    int c0 = (t & 15) * 4;
    float acc[4][4] = {};
#pragma unroll
    for (int k = 0; k < 64; k += 4) {
        float4 v0 = *(float4*)&Bs[k + 0][c0];
        float4 v1 = *(float4*)&Bs[k + 1][c0];
        float4 v2 = *(float4*)&Bs[k + 2][c0];
        float4 v3 = *(float4*)&Bs[k + 3][c0];
#pragma unroll
        for (int i = 0; i < 4; ++i) {
            float4 av = *(float4*)&As[r0 + i][k];
            acc[i][0] = fmaf(av.x, v0.x, fmaf(av.y, v1.x, fmaf(av.z, v2.x, fmaf(av.w, v3.x, acc[i][0]))));
            acc[i][1] = fmaf(av.x, v0.y, fmaf(av.y, v1.y, fmaf(av.z, v2.y, fmaf(av.w, v3.y, acc[i][1]))));
            acc[i][2] = fmaf(av.x, v0.z, fmaf(av.y, v1.z, fmaf(av.z, v2.z, fmaf(av.w, v3.z, acc[i][2]))));
            acc[i][3] = fmaf(av.x, v0.w, fmaf(av.y, v1.w, fmaf(av.z, v2.w, fmaf(av.w, v3.w, acc[i][3]))));
        }
    }
    float4 bv1 = *(const float4*)&b1[c0];
    __syncthreads();
#pragma unroll
    for (int i = 0; i < 4; ++i) {
        float4 y;
        y.x = fmaxf(acc[i][0] + bv1.x, 0.f);
        y.y = fmaxf(acc[i][1] + bv1.y, 0.f);
        y.z = fmaxf(acc[i][2] + bv1.z, 0.f);
        y.w = fmaxf(acc[i][3] + bv1.w, 0.f);
        *(float4*)&As[r0 + i][c0] = y;
    }
#pragma unroll
    for (int i = 0; i < 4; ++i) {
        int idx = t + i * 256;
        int r = idx >> 4, c = (idx & 15) << 2;
        *(float4*)&Bs[r][c] = *(const float4*)&W2[r * DIM + c];
    }
    __syncthreads();
    float acc2[4][4] = {};
#pragma unroll
    for (int k = 0; k < 64; k += 4) {
        float4 v0 = *(float4*)&Bs[k + 0][c0];
        float4 v1 = *(float4*)&Bs[k + 1][c0];
        float4 v2 = *(float4*)&Bs[k + 2][c0];
        float4 v3 = *(float4*)&Bs[k + 3][c0];
#pragma unroll
        for (int i = 0; i < 4; ++i) {
            float4 av = *(float4*)&As[r0 + i][k];
            acc2[i][0] = fmaf(av.x, v0.x, fmaf(av.y, v1.x, fmaf(av.z, v2.x, fmaf(av.w, v3.x, acc2[i][0]))));
            acc2[i][1] = fmaf(av.x, v0.y, fmaf(av.y, v1.y, fmaf(av.z, v2.y, fmaf(av.w, v3.y, acc2[i][1]))));
            acc2[i][2] = fmaf(av.x, v0.z, fmaf(av.y, v1.z, fmaf(av.z, v2.z, fmaf(av.w, v3.z, acc2[i][2]))));
            acc2[i][3] = fmaf(av.x, v0.w, fmaf(av.y, v1.w, fmaf(av.z, v2.w, fmaf(av.w, v3.w, acc2[i][3]))));
        }
    }
    float4 bv2 = *(const float4*)&b2[c0];
#pragma unroll
    for (int i = 0; i < 4; ++i) {
        int r = n0 + r0 + i;
        if (r < NN) {
            __half2 p0 = __floats2half2_rn(acc2[i][0] + bv2.x, acc2[i][1] + bv2.y);
            __half2 p1 = __floats2half2_rn(acc2[i][2] + bv2.z, acc2[i][3] + bv2.w);
            uint2 pk;
            pk.x = *(unsigned int*)&p0;
            pk.y = *(unsigned int*)&p1;
            *(uint2*)&Zh[(size_t)r * DIM + c0] = pk;
        }
    }
}

// last layer: agg + relu(X@W+b) -> colsum; last block computes the output.
__global__ __launch_bounds__(256, 4) void k_layer_last(const uint2* __restrict__ Hq,
                                                       const float* __restrict__ dis,
                                                       const int* __restrict__ row_ptr,
                                                       const int* __restrict__ edges,
                                                       const float* __restrict__ W,
                                                       const float* __restrict__ bias,
                                                       float* __restrict__ colsum,
                                                       int* __restrict__ done,
                                                       const float* __restrict__ out_w,
                                                       const float* __restrict__ out_b,
                                                       float* __restrict__ out) {
    __shared__ float As[64][68];
    __shared__ float Bs[64][64];
    __shared__ int se[4][64];
    __shared__ int is_last;
    int t = threadIdx.x;
    int n0 = blockIdx.x * 64;

    agg_tile(As, se, Hq, dis, row_ptr, edges, n0);
    __syncthreads();

#pragma unroll
    for (int i = 0; i < 4; ++i) {
        int idx = t + i * 256;
        int r = idx >> 4, c = (idx & 15) << 2;
        *(float4*)&Bs[r][c] = *(const float4*)&W[r * DIM + c];
    }
    __syncthreads();
    int r0 = (t >> 4) * 4;
    int c0 = (t & 15) * 4;
    float acc[4][4] = {};
#pragma unroll
    for (int k = 0; k < 64; k += 4) {
        float4 b0 = *(float4*)&Bs[k + 0][c0];
        float4 b1 = *(float4*)&Bs[k + 1][c0];
        float4 b2 = *(float4*)&Bs[k + 2][c0];
        float4 b3 = *(float4*)&Bs[k + 3][c0];
#pragma unroll
        for (int i = 0; i < 4; ++i) {
            float4 av = *(float4*)&As[r0 + i][k];
            acc[i][0] = fmaf(av.x, b0.x, fmaf(av.y, b1.x, fmaf(av.z, b2.x, fmaf(av.w, b3.x, acc[i][0]))));
            acc[i][1] = fmaf(av.x, b0.y, fmaf(av.y, b1.y, fmaf(av.z, b2.y, fmaf(av.w, b3.y, acc[i][1]))));
            acc[i][2] = fmaf(av.x, b0.z, fmaf(av.y, b1.z, fmaf(av.z, b2.z, fmaf(av.w, b3.z, acc[i][2]))));
            acc[i][3] = fmaf(av.x, b0.w, fmaf(av.y, b1.w, fmaf(av.z, b2.w, fmaf(av.w, b3.w, acc[i][3]))));
        }
    }
    float4 bv = *(const float4*)&bias[c0];
    float csum[4] = {0.f, 0.f, 0.f, 0.f};
#pragma unroll
    for (int i = 0; i < 4; ++i) {
        int r = n0 + r0 + i;
        if (r < NN) {
            csum[0] += fmaxf(acc[i][0] + bv.x, 0.f);
            csum[1] += fmaxf(acc[i][1] + bv.y, 0.f);
            csum[2] += fmaxf(acc[i][2] + bv.z, 0.f);
            csum[3] += fmaxf(acc[i][3] + bv.w, 0.f);
        }
    }
    float* red = &As[0][0];
    __syncthreads();
    *(float4*)&red[(t >> 4) * 64 + c0] = make_float4(csum[0], csum[1], csum[2], csum[3]);
    __syncthreads();
    if (t < 64) {
        float s = 0.f;
#pragma unroll
        for (int g = 0; g < 16; ++g) s += red[g * 64 + t];
        atomicAdd(&colsum[t], s);
    }
    // last-block readout (canonical threadfence-reduction tail)
    __threadfence();
    __syncthreads();
    if (t == 0) {
        int old = atomicAdd(done, 1);
        is_last = (old == GB - 1);
    }
    __syncthreads();
    if (is_last && t < 64) {
        // memory-side read (atomic RMW +0) avoids any stale per-XCD L2 copy
        float v = atomicAdd(&colsum[t], 0.0f) * (1.0f / (float)NN) * out_w[t];
        for (int off = 32; off; off >>= 1) v += __shfl_down(v, off, 64);
        if (t == 0) out[0] = v + out_b[0];
    }
}

extern "C" void kernel_launch(void* const* d_in, const int* in_sizes, int n_in,
                              void* d_out, int out_size, void* d_ws, size_t ws_size,
                              hipStream_t stream) {
    const float* H  = (const float*)d_in[0];
    const int*   ei = (const int*)d_in[1];
    const float* enc_w[3] = { (const float*)d_in[3], (const float*)d_in[7],  (const float*)d_in[11] };
    const float* enc_b[3] = { (const float*)d_in[4], (const float*)d_in[8],  (const float*)d_in[12] };
    const float* upd_w[3] = { (const float*)d_in[5], (const float*)d_in[9],  (const float*)d_in[13] };
    const float* upd_b[3] = { (const float*)d_in[6], (const float*)d_in[10], (const float*)d_in[14] };
    const float* out_w = (const float*)d_in[15];
    const float* out_b = (const float*)d_in[16];
    float* out = (float*)d_out;

    size_t off = 0;
    auto carve = [&](size_t bytes) {
        void* p = (char*)d_ws + off;
        off = (off + bytes + 255) & ~(size_t)255;
        return p;
    };
    int*    lpart_u = (int*)carve((size_t)SLICES * (NB + 1) * 4);
    int*    lpart_v = (int*)carve((size_t)SLICES * (NB + 1) * 4);
    int*    tot     = (int*)carve((size_t)NB * 4);
    float*  dis     = (float*)carve((size_t)NN * 4);
    ushort* usort   = (ushort*)carve((size_t)SLICES * ES * 2);
    int*    ebuf    = (int*)carve((size_t)SLICES * ES * 4);
    int*    edges   = (int*)carve((size_t)NE * 4);
    int*    row_ptr = (int*)carve((size_t)(NN + 65) * 4);
    __half* Ch      = (__half*)carve((size_t)NN * DIM * 2);
    __half* Ch2     = (__half*)carve((size_t)NN * DIM * 2);
    float*  colsum  = (float*)carve(64 * 4);
    int*    done    = (int*)carve(4);

    const uint2* Hq  = (const uint2*)Ch;
    const uint2* Hq2 = (const uint2*)Ch2;

    k_lsort<<<SLICES, 256, 0, stream>>>(ei, usort, ebuf, lpart_u, lpart_v);
    k_gemm_h<<<GB, 256, 0, stream>>>(H, enc_w[0], enc_b[0], Ch, NN);
    k_mid<<<2 * BB, 256, 0, stream>>>(usort, lpart_u, lpart_v, dis, tot, colsum, done);
    k_vsort<<<BB, 256, 0, stream>>>(ebuf, lpart_v, tot, dis, edges, row_ptr);

    k_layer<<<GB, 256, 0, stream>>>(Hq, dis, row_ptr, edges,
                                    upd_w[0], upd_b[0], enc_w[1], enc_b[1], Ch2);
    k_layer<<<GB, 256, 0, stream>>>(Hq2, dis, row_ptr, edges,
                                    upd_w[1], upd_b[1], enc_w[2], enc_b[2], Ch);
    k_layer_last<<<GB, 256, 0, stream>>>(Hq, dis, row_ptr, edges,
                                         upd_w[2], upd_b[2], colsum, done,
                                         out_w, out_b, out);
}

// Round 15
// 432.299 us; speedup vs baseline: 2.4449x; 2.4449x over previous
//
#include <hip/hip_runtime.h>
#include <hip/hip_fp16.h>

#define NN 50000
#define NE 1200000
#define DIM 64
#define NB 782            // node buckets of 64: ceil(50000/64)
#define BB 196            // ceil(NB/4)
#define SLICES 256
#define ES 4688           // ceil(NE/SLICES)
#define VCAP 2048         // vsort bucket cache cap (mean 1536, ~13 sigma)
#define GB 782            // gemm blocks: ceil(NN/64)
#define FRONT_LDS 34048   // max(lsort ~32.3KB, gemm 33.8KB)

// ================= fused front kernel bodies =================

// slice bucket-sort body (blocks 0..SLICES-1)
__device__ __forceinline__ void lsort_body(char* smem, const int* __restrict__ ei,
                                           ushort* __restrict__ usort,
                                           int* __restrict__ ebuf,
                                           int* __restrict__ lpart_u,
                                           int* __restrict__ lpart_v) {
    int* hist = (int*)smem;                       // (NB+1)*4 -> pad 3136
    int* scratch = (int*)(smem + 3136);           // 1024
    ushort* sbu = (ushort*)(smem + 4160);         // ES*2 = 9376
    int* sbv = (int*)(smem + 13568);              // ES*4 = 18752
    int t = threadIdx.x, s = blockIdx.x;
    int e0 = s * ES, e1 = min(e0 + ES, NE), len = e1 - e0;
    int i0 = t * 4;

    // ======== pass U
    for (int i = t; i < NB; i += 256) hist[i] = 0;
    __syncthreads();
    for (int e = e0 + t; e < e1; e += 256) atomicAdd(&hist[ei[e] >> 6], 1);
    __syncthreads();
    {
        int h0 = (i0 + 0 < NB) ? hist[i0 + 0] : 0;
        int h1 = (i0 + 1 < NB) ? hist[i0 + 1] : 0;
        int h2 = (i0 + 2 < NB) ? hist[i0 + 2] : 0;
        int h3 = (i0 + 3 < NB) ? hist[i0 + 3] : 0;
        int p1 = h0, p2 = h0 + h1, p3 = p2 + h2, p4 = p3 + h3;
        scratch[t] = p4;
        __syncthreads();
        for (int off = 1; off < 256; off <<= 1) {
            int x = 0;
            if (t >= off) x = scratch[t - off];
            __syncthreads();
            scratch[t] += x;
            __syncthreads();
        }
        int excl = scratch[t] - p4;
        int* lpu = lpart_u + s * (NB + 1);
        if (i0 + 0 < NB) { lpu[i0 + 0] = excl;      hist[i0 + 0] = excl; }
        if (i0 + 1 < NB) { lpu[i0 + 1] = excl + p1; hist[i0 + 1] = excl + p1; }
        if (i0 + 2 < NB) { lpu[i0 + 2] = excl + p2; hist[i0 + 2] = excl + p2; }
        if (i0 + 3 < NB) { lpu[i0 + 3] = excl + p3; hist[i0 + 3] = excl + p3; }
        if (t == 255) lpu[NB] = scratch[255];
    }
    __syncthreads();
    for (int e = e0 + t; e < e1; e += 256) {
        int u = ei[e];
        int pos = atomicAdd(&hist[u >> 6], 1);
        sbu[pos] = (ushort)u;
    }
    __syncthreads();
    for (int i = t; i < len; i += 256) usort[e0 + i] = sbu[i];
    __syncthreads();

    // ======== pass V
    for (int i = t; i < NB; i += 256) hist[i] = 0;
    __syncthreads();
    for (int e = e0 + t; e < e1; e += 256) atomicAdd(&hist[ei[NE + e] >> 6], 1);
    __syncthreads();
    {
        int h0 = (i0 + 0 < NB) ? hist[i0 + 0] : 0;
        int h1 = (i0 + 1 < NB) ? hist[i0 + 1] : 0;
        int h2 = (i0 + 2 < NB) ? hist[i0 + 2] : 0;
        int h3 = (i0 + 3 < NB) ? hist[i0 + 3] : 0;
        int p1 = h0, p2 = h0 + h1, p3 = p2 + h2, p4 = p3 + h3;
        scratch[t] = p4;
        __syncthreads();
        for (int off = 1; off < 256; off <<= 1) {
            int x = 0;
            if (t >= off) x = scratch[t - off];
            __syncthreads();
            scratch[t] += x;
            __syncthreads();
        }
        int excl = scratch[t] - p4;
        int* lpv = lpart_v + s * (NB + 1);
        if (i0 + 0 < NB) { lpv[i0 + 0] = excl;      hist[i0 + 0] = excl; }
        if (i0 + 1 < NB) { lpv[i0 + 1] = excl + p1; hist[i0 + 1] = excl + p1; }
        if (i0 + 2 < NB) { lpv[i0 + 2] = excl + p2; hist[i0 + 2] = excl + p2; }
        if (i0 + 3 < NB) { lpv[i0 + 3] = excl + p3; hist[i0 + 3] = excl + p3; }
        if (t == 255) lpv[NB] = scratch[255];
    }
    __syncthreads();
    for (int e = e0 + t; e < e1; e += 256) {
        int u = ei[e], v = ei[NE + e];
        int pos = atomicAdd(&hist[v >> 6], 1);
        sbv[pos] = u | ((v & 63) << 16);
    }
    __syncthreads();
    for (int i = t; i < len; i += 256) ebuf[e0 + i] = sbv[i];
}

// fp32 GEMM body -> fp16 out. smem: As[64][68] | Bs[64][64]
__device__ __forceinline__ void gemm_h_body(char* smem, int blk,
                                            const float* __restrict__ A,
                                            const float* __restrict__ W,
                                            const float* __restrict__ bias,
                                            __half* __restrict__ Ch, int M) {
    float (*As)[68] = (float(*)[68])smem;
    float (*Bs)[64] = (float(*)[64])(smem + 17408);
    int t = threadIdx.x;
    int row0 = blk * 64;
#pragma unroll
    for (int i = 0; i < 4; ++i) {
        int idx = t + i * 256;
        int r = idx >> 4, c = (idx & 15) << 2;
        float4 val = make_float4(0.f, 0.f, 0.f, 0.f);
        if (row0 + r < M) val = *(const float4*)&A[(size_t)(row0 + r) * DIM + c];
        *(float4*)&As[r][c] = val;
        *(float4*)&Bs[r][c] = *(const float4*)&W[r * DIM + c];
    }
    __syncthreads();
    int r0 = (t >> 4) * 4;
    int c0 = (t & 15) * 4;
    float acc[4][4] = {};
#pragma unroll
    for (int k = 0; k < 64; k += 4) {
        float4 b0 = *(float4*)&Bs[k + 0][c0];
        float4 b1 = *(float4*)&Bs[k + 1][c0];
        float4 b2 = *(float4*)&Bs[k + 2][c0];
        float4 b3 = *(float4*)&Bs[k + 3][c0];
#pragma unroll
        for (int i = 0; i < 4; ++i) {
            float4 av = *(float4*)&As[r0 + i][k];
            acc[i][0] = fmaf(av.x, b0.x, fmaf(av.y, b1.x, fmaf(av.z, b2.x, fmaf(av.w, b3.x, acc[i][0]))));
            acc[i][1] = fmaf(av.x, b0.y, fmaf(av.y, b1.y, fmaf(av.z, b2.y, fmaf(av.w, b3.y, acc[i][1]))));
            acc[i][2] = fmaf(av.x, b0.z, fmaf(av.y, b1.z, fmaf(av.z, b2.z, fmaf(av.w, b3.z, acc[i][2]))));
            acc[i][3] = fmaf(av.x, b0.w, fmaf(av.y, b1.w, fmaf(av.z, b2.w, fmaf(av.w, b3.w, acc[i][3]))));
        }
    }
    float4 bv = *(const float4*)&bias[c0];
#pragma unroll
    for (int i = 0; i < 4; ++i) {
        int r = row0 + r0 + i;
        if (r < M) {
            __half2 p0 = __floats2half2_rn(acc[i][0] + bv.x, acc[i][1] + bv.y);
            __half2 p1 = __floats2half2_rn(acc[i][2] + bv.z, acc[i][3] + bv.w);
            uint2 pk;
            pk.x = *(unsigned int*)&p0;
            pk.y = *(unsigned int*)&p1;
            *(uint2*)&Ch[(size_t)r * DIM + c0] = pk;
        }
    }
}

// fused front: blocks [0,SLICES) = slice sort; [SLICES, SLICES+GB) = enc GEMM 0
__global__ __launch_bounds__(256) void k_front(const int* __restrict__ ei,
                                               ushort* __restrict__ usort,
                                               int* __restrict__ ebuf,
                                               int* __restrict__ lpart_u,
                                               int* __restrict__ lpart_v,
                                               const float* __restrict__ A,
                                               const float* __restrict__ W,
                                               const float* __restrict__ bias,
                                               __half* __restrict__ Ch) {
    extern __shared__ char smem[];
    if (blockIdx.x < SLICES)
        lsort_body(smem, ei, usort, ebuf, lpart_u, lpart_v);
    else
        gemm_h_body(smem, blockIdx.x - SLICES, A, W, bias, Ch, NN);
}

// ---------------- fused: [0,BB) u-count -> dis; [BB,2*BB) v-bucket totals.
// Block 0 zeroes colsum + done.
__global__ __launch_bounds__(256) void k_mid(const ushort* __restrict__ usort,
                                             const int* __restrict__ lpart_u,
                                             const int* __restrict__ lpart_v,
                                             float* __restrict__ dis,
                                             int* __restrict__ tot,
                                             float* __restrict__ colsum,
                                             int* __restrict__ done) {
    __shared__ int sh[4][64];
    int bid = blockIdx.x;
    if (bid == 0) {
        if (threadIdx.x < 64) colsum[threadIdx.x] = 0.f;
        if (threadIdx.x == 64) *done = 0;
    }
    int w = threadIdx.x >> 6, l = threadIdx.x & 63;
    if (bid < BB) {
        int b = bid * 4 + w;
        if (b >= NB) return;
        sh[w][l] = 0;
        __builtin_amdgcn_wave_barrier();
        for (int s = l; s < SLICES; s += 64) {
            const int* row = lpart_u + s * (NB + 1);
            int st = row[b], en = row[b + 1];
            for (int i = st; i < en; ++i)
                atomicAdd(&sh[w][usort[s * ES + i] & 63], 1);
        }
        __builtin_amdgcn_wave_barrier();
        int n = (b << 6) + l;
        if (n < NN) dis[n] = rsqrtf((float)sh[w][l] + 1.0f);
    } else {
        int c = (bid - BB) * 4 + w;
        if (c >= NB) return;
        int sum = 0;
        for (int s = l; s < SLICES; s += 64) {
            const int* row = lpart_v + s * (NB + 1);
            sum += row[c + 1] - row[c];
        }
        for (int off = 32; off; off >>= 1) sum += __shfl_down(sum, off, 64);
        if (l == 0) tot[c] = sum;
    }
}

// ---------------- per-bucket counting sort, LDS-cached; base_v self-computed.
__global__ __launch_bounds__(256) void k_vsort(const int* __restrict__ ebuf,
                                               const int* __restrict__ lpart_v,
                                               const int* __restrict__ tot,
                                               const float* __restrict__ dis,
                                               int* __restrict__ edges,
                                               int* __restrict__ row_ptr) {
    __shared__ int cache[4][VCAP];
    __shared__ int cnt[4][64];
    __shared__ int cur[4][64];
    int w = threadIdx.x >> 6, l = threadIdx.x & 63;
    int b = blockIdx.x * 4 + w;
    if (b >= NB) return;
    int partial = 0;
    for (int c = l; c < b; c += 64) partial += tot[c];
    for (int off = 32; off; off >>= 1) partial += __shfl_down(partial, off, 64);
    int rbase = __shfl(partial, 0, 64);
    int n = tot[b];
    cnt[w][l] = 0;
    __builtin_amdgcn_wave_barrier();
    if (n <= VCAP) {
        int len[4]; int tl = 0;
#pragma unroll
        for (int k = 0; k < 4; ++k) {
            const int* row = lpart_v + (l * 4 + k) * (NB + 1);
            len[k] = row[b + 1] - row[b];
            tl += len[k];
        }
        int inc = tl;
        for (int o = 1; o < 64; o <<= 1) {
            int x = __shfl_up(inc, o, 64);
            if (l >= o) inc += x;
        }
        int pos = inc - tl;
#pragma unroll
        for (int k = 0; k < 4; ++k) {
            int s = l * 4 + k;
            const int* row = lpart_v + s * (NB + 1);
            int st = row[b];
            for (int i = 0; i < len[k]; ++i)
                cache[w][pos++] = ebuf[s * ES + st + i];
        }
        __builtin_amdgcn_wave_barrier();
        for (int i = l; i < n; i += 64)
            atomicAdd(&cnt[w][(cache[w][i] >> 16) & 63], 1);
        __builtin_amdgcn_wave_barrier();
        int c = cnt[w][l];
        int inc2 = c;
        for (int o = 1; o < 64; o <<= 1) {
            int x = __shfl_up(inc2, o, 64);
            if (l >= o) inc2 += x;
        }
        int excl = inc2 - c;
        cur[w][l] = rbase + excl;
        row_ptr[(b << 6) + l] = rbase + excl;
        __builtin_amdgcn_wave_barrier();
        for (int i = l; i < n; i += 64) {
            int rec = cache[w][i];
            int u = rec & 0xFFFF;
            int p2 = atomicAdd(&cur[w][(rec >> 16) & 63], 1);
            ushort dh = __half_as_ushort(__float2half_rn(dis[u]));
            edges[p2] = u | ((int)dh << 16);
        }
    } else {
        for (int s = l; s < SLICES; s += 64) {
            const int* row = lpart_v + s * (NB + 1);
            int st = row[b], en = row[b + 1];
            for (int i = st; i < en; ++i)
                atomicAdd(&cnt[w][(ebuf[s * ES + i] >> 16) & 63], 1);
        }
        __builtin_amdgcn_wave_barrier();
        int c = cnt[w][l];
        int inc2 = c;
        for (int o = 1; o < 64; o <<= 1) {
            int x = __shfl_up(inc2, o, 64);
            if (l >= o) inc2 += x;
        }
        int excl = inc2 - c;
        cur[w][l] = rbase + excl;
        row_ptr[(b << 6) + l] = rbase + excl;
        __builtin_amdgcn_wave_barrier();
        for (int s = l; s < SLICES; s += 64) {
            const int* row = lpart_v + s * (NB + 1);
            int st = row[b], en = row[b + 1];
            for (int i = st; i < en; ++i) {
                int rec = ebuf[s * ES + i];
                int u = rec & 0xFFFF;
                int p2 = atomicAdd(&cur[w][(rec >> 16) & 63], 1);
                ushort dh = __half_as_ushort(__float2half_rn(dis[u]));
                edges[p2] = u | ((int)dh << 16);
            }
        }
    }
}

// ---------------- fused dual GEMM: Zh = half(relu(X@W1+b1)@W2 + b2)
__global__ __launch_bounds__(256) void k_gemm2(const float* __restrict__ X,
                                               const float* __restrict__ W1,
                                               const float* __restrict__ b1,
                                               const float* __restrict__ W2,
                                               const float* __restrict__ b2,
                                               __half* __restrict__ Zh, int M) {
    __shared__ float As[64][68];
    __shared__ float Bs[64][64];
    int t = threadIdx.x;
    int row0 = blockIdx.x * 64;
#pragma unroll
    for (int i = 0; i < 4; ++i) {
        int idx = t + i * 256;
        int r = idx >> 4, c = (idx & 15) << 2;
        float4 val = make_float4(0.f, 0.f, 0.f, 0.f);
        if (row0 + r < M) val = *(const float4*)&X[(size_t)(row0 + r) * DIM + c];
        *(float4*)&As[r][c] = val;
        *(float4*)&Bs[r][c] = *(const float4*)&W1[r * DIM + c];
    }
    __syncthreads();
    int r0 = (t >> 4) * 4;
    int c0 = (t & 15) * 4;
    float acc[4][4] = {};
#pragma unroll
    for (int k = 0; k < 64; k += 4) {
        float4 v0 = *(float4*)&Bs[k + 0][c0];
        float4 v1 = *(float4*)&Bs[k + 1][c0];
        float4 v2 = *(float4*)&Bs[k + 2][c0];
        float4 v3 = *(float4*)&Bs[k + 3][c0];
#pragma unroll
        for (int i = 0; i < 4; ++i) {
            float4 av = *(float4*)&As[r0 + i][k];
            acc[i][0] = fmaf(av.x, v0.x, fmaf(av.y, v1.x, fmaf(av.z, v2.x, fmaf(av.w, v3.x, acc[i][0]))));
            acc[i][1] = fmaf(av.x, v0.y, fmaf(av.y, v1.y, fmaf(av.z, v2.y, fmaf(av.w, v3.y, acc[i][1]))));
            acc[i][2] = fmaf(av.x, v0.z, fmaf(av.y, v1.z, fmaf(av.z, v2.z, fmaf(av.w, v3.z, acc[i][2]))));
            acc[i][3] = fmaf(av.x, v0.w, fmaf(av.y, v1.w, fmaf(av.z, v2.w, fmaf(av.w, v3.w, acc[i][3]))));
        }
    }
    float4 bv1 = *(const float4*)&b1[c0];
    __syncthreads();
#pragma unroll
    for (int i = 0; i < 4; ++i) {
        float4 y;
        y.x = fmaxf(acc[i][0] + bv1.x, 0.f);
        y.y = fmaxf(acc[i][1] + bv1.y, 0.f);
        y.z = fmaxf(acc[i][2] + bv1.z, 0.f);
        y.w = fmaxf(acc[i][3] + bv1.w, 0.f);
        *(float4*)&As[r0 + i][c0] = y;
    }
#pragma unroll
    for (int i = 0; i < 4; ++i) {
        int idx = t + i * 256;
        int r = idx >> 4, c = (idx & 15) << 2;
        *(float4*)&Bs[r][c] = *(const float4*)&W2[r * DIM + c];
    }
    __syncthreads();
    float acc2[4][4] = {};
#pragma unroll
    for (int k = 0; k < 64; k += 4) {
        float4 v0 = *(float4*)&Bs[k + 0][c0];
        float4 v1 = *(float4*)&Bs[k + 1][c0];
        float4 v2 = *(float4*)&Bs[k + 2][c0];
        float4 v3 = *(float4*)&Bs[k + 3][c0];
#pragma unroll
        for (int i = 0; i < 4; ++i) {
            float4 av = *(float4*)&As[r0 + i][k];
            acc2[i][0] = fmaf(av.x, v0.x, fmaf(av.y, v1.x, fmaf(av.z, v2.x, fmaf(av.w, v3.x, acc2[i][0]))));
            acc2[i][1] = fmaf(av.x, v0.y, fmaf(av.y, v1.y, fmaf(av.z, v2.y, fmaf(av.w, v3.y, acc2[i][1]))));
            acc2[i][2] = fmaf(av.x, v0.z, fmaf(av.y, v1.z, fmaf(av.z, v2.z, fmaf(av.w, v3.z, acc2[i][2]))));
            acc2[i][3] = fmaf(av.x, v0.w, fmaf(av.y, v1.w, fmaf(av.z, v2.w, fmaf(av.w, v3.w, acc2[i][3]))));
        }
    }
    float4 bv2 = *(const float4*)&b2[c0];
#pragma unroll
    for (int i = 0; i < 4; ++i) {
        int r = row0 + r0 + i;
        if (r < M) {
            __half2 p0 = __floats2half2_rn(acc2[i][0] + bv2.x, acc2[i][1] + bv2.y);
            __half2 p1 = __floats2half2_rn(acc2[i][2] + bv2.z, acc2[i][3] + bv2.w);
            uint2 pk;
            pk.x = *(unsigned int*)&p0;
            pk.y = *(unsigned int*)&p1;
            *(uint2*)&Zh[(size_t)r * DIM + c0] = pk;
        }
    }
}

// ---------------- last GEMM: relu(X@W+b) -> colsum; last block emits output
__global__ __launch_bounds__(256) void k_gemm_last(const float* __restrict__ A,
                                                   const float* __restrict__ W,
                                                   const float* __restrict__ bias,
                                                   int M, float* __restrict__ colsum,
                                                   int* __restrict__ done,
                                                   const float* __restrict__ out_w,
                                                   const float* __restrict__ out_b,
                                                   float* __restrict__ out) {
    __shared__ float As[64][68];
    __shared__ float Bs[64][64];
    __shared__ int is_last;
    int t = threadIdx.x;
    int row0 = blockIdx.x * 64;
#pragma unroll
    for (int i = 0; i < 4; ++i) {
        int idx = t + i * 256;
        int r = idx >> 4, c = (idx & 15) << 2;
        float4 val = make_float4(0.f, 0.f, 0.f, 0.f);
        if (row0 + r < M) val = *(const float4*)&A[(size_t)(row0 + r) * DIM + c];
        *(float4*)&As[r][c] = val;
        *(float4*)&Bs[r][c] = *(const float4*)&W[r * DIM + c];
    }
    __syncthreads();
    int r0 = (t >> 4) * 4;
    int c0 = (t & 15) * 4;
    float acc[4][4] = {};
#pragma unroll
    for (int k = 0; k < 64; k += 4) {
        float4 b0 = *(float4*)&Bs[k + 0][c0];
        float4 b1 = *(float4*)&Bs[k + 1][c0];
        float4 b2 = *(float4*)&Bs[k + 2][c0];
        float4 b3 = *(float4*)&Bs[k + 3][c0];
#pragma unroll
        for (int i = 0; i < 4; ++i) {
            float4 av = *(float4*)&As[r0 + i][k];
            acc[i][0] = fmaf(av.x, b0.x, fmaf(av.y, b1.x, fmaf(av.z, b2.x, fmaf(av.w, b3.x, acc[i][0]))));
            acc[i][1] = fmaf(av.x, b0.y, fmaf(av.y, b1.y, fmaf(av.z, b2.y, fmaf(av.w, b3.y, acc[i][1]))));
            acc[i][2] = fmaf(av.x, b0.z, fmaf(av.y, b1.z, fmaf(av.z, b2.z, fmaf(av.w, b3.z, acc[i][2]))));
            acc[i][3] = fmaf(av.x, b0.w, fmaf(av.y, b1.w, fmaf(av.z, b2.w, fmaf(av.w, b3.w, acc[i][3]))));
        }
    }
    float4 bv = *(const float4*)&bias[c0];
    float csum[4] = {0.f, 0.f, 0.f, 0.f};
#pragma unroll
    for (int i = 0; i < 4; ++i) {
        int r = row0 + r0 + i;
        if (r < M) {
            csum[0] += fmaxf(acc[i][0] + bv.x, 0.f);
            csum[1] += fmaxf(acc[i][1] + bv.y, 0.f);
            csum[2] += fmaxf(acc[i][2] + bv.z, 0.f);
            csum[3] += fmaxf(acc[i][3] + bv.w, 0.f);
        }
    }
    float* red = &As[0][0];
    __syncthreads();
    *(float4*)&red[(t >> 4) * 64 + c0] = make_float4(csum[0], csum[1], csum[2], csum[3]);
    __syncthreads();
    if (t < 64) {
        float s = 0.f;
#pragma unroll
        for (int g = 0; g < 16; ++g) s += red[g * 64 + t];
        atomicAdd(&colsum[t], s);
    }
    // last-block readout
    __threadfence();
    __syncthreads();
    if (t == 0) {
        int old = atomicAdd(done, 1);
        is_last = (old == GB - 1);
    }
    __syncthreads();
    if (is_last && t < 64) {
        float v = atomicAdd(&colsum[t], 0.0f) * (1.0f / (float)NN) * out_w[t];
        for (int off = 32; off; off >>= 1) v += __shfl_down(v, off, 64);
        if (t == 0) out[0] = v + out_b[0];
    }
}

// ---------------- aggregation: wave per node, ALWAYS 8-deep gather pipeline
__global__ __launch_bounds__(256) void k_agg(const uint2* __restrict__ Hq,
                                             const float* __restrict__ dis,
                                             const int* __restrict__ row_ptr,
                                             const int* __restrict__ edges,
                                             float* __restrict__ X) {
    __shared__ int se[4][64];
    int w = threadIdx.x >> 6, l = threadIdx.x & 63;
    int node = (blockIdx.x << 2) + w;
    if (node >= NN) return;
    int start = row_ptr[node];
    int num = row_ptr[node + 1] - start;
    int g = l >> 4;           // edge subgroup 0..3
    int p = l & 15;           // feature quad 0..15
    float4 acc = {0.f, 0.f, 0.f, 0.f};
    for (int base = 0; base < num; base += 64) {
        int lim = min(64, num - base);
        se[w][l] = (l < lim) ? edges[start + base + l] : 0;
        __builtin_amdgcn_wave_barrier();
        int quads = (lim + 3) >> 2;          // 1..16
        for (int j = 0; j < quads; j += 8) {
            int rr[8]; uint2 hh[8];
#pragma unroll
            for (int q = 0; q < 8; ++q) rr[q] = se[w][4 * (j + q) + g];
#pragma unroll
            for (int q = 0; q < 8; ++q) hh[q] = Hq[((rr[q] & 0xFFFF) << 4) + p];
#pragma unroll
            for (int q = 0; q < 8; ++q) {
                float wt = __half2float(__ushort_as_half((ushort)((unsigned)rr[q] >> 16)));
                float2 f0 = __half22float2(*(const __half2*)&hh[q].x);
                float2 f1 = __half22float2(*(const __half2*)&hh[q].y);
                acc.x = fmaf(wt, f0.x, acc.x);
                acc.y = fmaf(wt, f0.y, acc.y);
                acc.z = fmaf(wt, f1.x, acc.z);
                acc.w = fmaf(wt, f1.y, acc.w);
            }
        }
        __builtin_amdgcn_wave_barrier();
    }
#pragma unroll
    for (int m = 16; m < 64; m <<= 1) {
        acc.x += __shfl_xor(acc.x, m, 64);
        acc.y += __shfl_xor(acc.y, m, 64);
        acc.z += __shfl_xor(acc.z, m, 64);
        acc.w += __shfl_xor(acc.w, m, 64);
    }
    if (g == 0) {
        uint2 sv = Hq[(node << 4) + p];
        float2 s0 = __half22float2(*(const __half2*)&sv.x);
        float2 s1 = __half22float2(*(const __half2*)&sv.y);
        float dv = dis[node];
        float4 o;
        o.x = fmaf(dv, acc.x, s0.x);
        o.y = fmaf(dv, acc.y, s0.y);
        o.z = fmaf(dv, acc.z, s1.x);
        o.w = fmaf(dv, acc.w, s1.y);
        *(float4*)&X[((size_t)node << 6) + (p << 2)] = o;
    }
}

extern "C" void kernel_launch(void* const* d_in, const int* in_sizes, int n_in,
                              void* d_out, int out_size, void* d_ws, size_t ws_size,
                              hipStream_t stream) {
    const float* H  = (const float*)d_in[0];
    const int*   ei = (const int*)d_in[1];
    const float* enc_w[3] = { (const float*)d_in[3], (const float*)d_in[7],  (const float*)d_in[11] };
    const float* enc_b[3] = { (const float*)d_in[4], (const float*)d_in[8],  (const float*)d_in[12] };
    const float* upd_w[3] = { (const float*)d_in[5], (const float*)d_in[9],  (const float*)d_in[13] };
    const float* upd_b[3] = { (const float*)d_in[6], (const float*)d_in[10], (const float*)d_in[14] };
    const float* out_w = (const float*)d_in[15];
    const float* out_b = (const float*)d_in[16];
    float* out = (float*)d_out;

    size_t off = 0;
    auto carve = [&](size_t bytes) {
        void* p = (char*)d_ws + off;
        off = (off + bytes + 255) & ~(size_t)255;
        return p;
    };
    int*    lpart_u = (int*)carve((size_t)SLICES * (NB + 1) * 4);
    int*    lpart_v = (int*)carve((size_t)SLICES * (NB + 1) * 4);
    int*    tot     = (int*)carve((size_t)NB * 4);
    float*  dis     = (float*)carve((size_t)NN * 4);
    ushort* usort   = (ushort*)carve((size_t)SLICES * ES * 2);
    int*    ebuf    = (int*)carve((size_t)SLICES * ES * 4);
    int*    edges   = (int*)carve((size_t)NE * 4);
    int*    row_ptr = (int*)carve((size_t)(NN + 65) * 4);
    __half* Ch      = (__half*)carve((size_t)NN * DIM * 2);
    float*  X       = (float*)carve((size_t)NN * DIM * 4);
    float*  colsum  = (float*)carve(64 * 4);
    int*    done    = (int*)carve(4);

    const int AB = (NN + 3) / 4;     // 12500
    const uint2* Hq = (const uint2*)Ch;

    // front: slice-sort (256 blocks) overlapped with enc-GEMM-0 (782 blocks)
    k_front<<<SLICES + GB, 256, FRONT_LDS, stream>>>(ei, usort, ebuf, lpart_u, lpart_v,
                                                     H, enc_w[0], enc_b[0], Ch);
    k_mid<<<2 * BB, 256, 0, stream>>>(usort, lpart_u, lpart_v, dis, tot, colsum, done);
    k_vsort<<<BB, 256, 0, stream>>>(ebuf, lpart_v, tot, dis, edges, row_ptr);

    k_agg<<<AB, 256, 0, stream>>>(Hq, dis, row_ptr, edges, X);
    k_gemm2<<<GB, 256, 0, stream>>>(X, upd_w[0], upd_b[0], enc_w[1], enc_b[1], Ch, NN);
    k_agg<<<AB, 256, 0, stream>>>(Hq, dis, row_ptr, edges, X);
    k_gemm2<<<GB, 256, 0, stream>>>(X, upd_w[1], upd_b[1], enc_w[2], enc_b[2], Ch, NN);
    k_agg<<<AB, 256, 0, stream>>>(Hq, dis, row_ptr, edges, X);
    k_gemm_last<<<GB, 256, 0, stream>>>(X, upd_w[2], upd_b[2], NN, colsum, done,
                                        out_w, out_b, out);
}

// Round 16
// 395.946 us; speedup vs baseline: 2.6694x; 1.0918x over previous
//
#include <hip/hip_runtime.h>
#include <hip/hip_fp16.h>

#define NN 50000
#define NE 1200000
#define DIM 64
#define NB 782            // node buckets of 64: ceil(50000/64)
#define BB 196            // ceil(NB/4)
#define SLICES 256
#define ES 4688           // ceil(NE/SLICES)
#define VCAP 2048         // vsort bucket cache cap (mean 1536, ~13 sigma)
#define GB 782            // gemm blocks: ceil(NN/64)
#define FRONT_LDS 34048   // max(lsort ~32.3KB, gemm 33.8KB)

// ================= fused front kernel bodies =================

// slice bucket-sort body (blocks 0..SLICES-1)
__device__ __forceinline__ void lsort_body(char* smem, const int* __restrict__ ei,
                                           ushort* __restrict__ usort,
                                           int* __restrict__ ebuf,
                                           int* __restrict__ lpart_u,
                                           int* __restrict__ lpart_v) {
    int* hist = (int*)smem;                       // (NB+1)*4 -> pad 3136
    int* scratch = (int*)(smem + 3136);           // 1024
    ushort* sbu = (ushort*)(smem + 4160);         // ES*2 = 9376
    int* sbv = (int*)(smem + 13568);              // ES*4 = 18752
    int t = threadIdx.x, s = blockIdx.x;
    int e0 = s * ES, e1 = min(e0 + ES, NE), len = e1 - e0;
    int i0 = t * 4;

    // ======== pass U
    for (int i = t; i < NB; i += 256) hist[i] = 0;
    __syncthreads();
    for (int e = e0 + t; e < e1; e += 256) atomicAdd(&hist[ei[e] >> 6], 1);
    __syncthreads();
    {
        int h0 = (i0 + 0 < NB) ? hist[i0 + 0] : 0;
        int h1 = (i0 + 1 < NB) ? hist[i0 + 1] : 0;
        int h2 = (i0 + 2 < NB) ? hist[i0 + 2] : 0;
        int h3 = (i0 + 3 < NB) ? hist[i0 + 3] : 0;
        int p1 = h0, p2 = h0 + h1, p3 = p2 + h2, p4 = p3 + h3;
        scratch[t] = p4;
        __syncthreads();
        for (int off = 1; off < 256; off <<= 1) {
            int x = 0;
            if (t >= off) x = scratch[t - off];
            __syncthreads();
            scratch[t] += x;
            __syncthreads();
        }
        int excl = scratch[t] - p4;
        int* lpu = lpart_u + s * (NB + 1);
        if (i0 + 0 < NB) { lpu[i0 + 0] = excl;      hist[i0 + 0] = excl; }
        if (i0 + 1 < NB) { lpu[i0 + 1] = excl + p1; hist[i0 + 1] = excl + p1; }
        if (i0 + 2 < NB) { lpu[i0 + 2] = excl + p2; hist[i0 + 2] = excl + p2; }
        if (i0 + 3 < NB) { lpu[i0 + 3] = excl + p3; hist[i0 + 3] = excl + p3; }
        if (t == 255) lpu[NB] = scratch[255];
    }
    __syncthreads();
    for (int e = e0 + t; e < e1; e += 256) {
        int u = ei[e];
        int pos = atomicAdd(&hist[u >> 6], 1);
        sbu[pos] = (ushort)u;
    }
    __syncthreads();
    for (int i = t; i < len; i += 256) usort[e0 + i] = sbu[i];
    __syncthreads();

    // ======== pass V
    for (int i = t; i < NB; i += 256) hist[i] = 0;
    __syncthreads();
    for (int e = e0 + t; e < e1; e += 256) atomicAdd(&hist[ei[NE + e] >> 6], 1);
    __syncthreads();
    {
        int h0 = (i0 + 0 < NB) ? hist[i0 + 0] : 0;
        int h1 = (i0 + 1 < NB) ? hist[i0 + 1] : 0;
        int h2 = (i0 + 2 < NB) ? hist[i0 + 2] : 0;
        int h3 = (i0 + 3 < NB) ? hist[i0 + 3] : 0;
        int p1 = h0, p2 = h0 + h1, p3 = p2 + h2, p4 = p3 + h3;
        scratch[t] = p4;
        __syncthreads();
        for (int off = 1; off < 256; off <<= 1) {
            int x = 0;
            if (t >= off) x = scratch[t - off];
            __syncthreads();
            scratch[t] += x;
            __syncthreads();
        }
        int excl = scratch[t] - p4;
        int* lpv = lpart_v + s * (NB + 1);
        if (i0 + 0 < NB) { lpv[i0 + 0] = excl;      hist[i0 + 0] = excl; }
        if (i0 + 1 < NB) { lpv[i0 + 1] = excl + p1; hist[i0 + 1] = excl + p1; }
        if (i0 + 2 < NB) { lpv[i0 + 2] = excl + p2; hist[i0 + 2] = excl + p2; }
        if (i0 + 3 < NB) { lpv[i0 + 3] = excl + p3; hist[i0 + 3] = excl + p3; }
        if (t == 255) lpv[NB] = scratch[255];
    }
    __syncthreads();
    for (int e = e0 + t; e < e1; e += 256) {
        int u = ei[e], v = ei[NE + e];
        int pos = atomicAdd(&hist[v >> 6], 1);
        sbv[pos] = u | ((v & 63) << 16);
    }
    __syncthreads();
    for (int i = t; i < len; i += 256) ebuf[e0 + i] = sbv[i];
}

// fp32 GEMM body -> fp16 out. smem: As[64][68] | Bs[64][64]
__device__ __forceinline__ void gemm_h_body(char* smem, int blk,
                                            const float* __restrict__ A,
                                            const float* __restrict__ W,
                                            const float* __restrict__ bias,
                                            __half* __restrict__ Ch, int M) {
    float (*As)[68] = (float(*)[68])smem;
    float (*Bs)[64] = (float(*)[64])(smem + 17408);
    int t = threadIdx.x;
    int row0 = blk * 64;
#pragma unroll
    for (int i = 0; i < 4; ++i) {
        int idx = t + i * 256;
        int r = idx >> 4, c = (idx & 15) << 2;
        float4 val = make_float4(0.f, 0.f, 0.f, 0.f);
        if (row0 + r < M) val = *(const float4*)&A[(size_t)(row0 + r) * DIM + c];
        *(float4*)&As[r][c] = val;
        *(float4*)&Bs[r][c] = *(const float4*)&W[r * DIM + c];
    }
    __syncthreads();
    int r0 = (t >> 4) * 4;
    int c0 = (t & 15) * 4;
    float acc[4][4] = {};
#pragma unroll
    for (int k = 0; k < 64; k += 4) {
        float4 b0 = *(float4*)&Bs[k + 0][c0];
        float4 b1 = *(float4*)&Bs[k + 1][c0];
        float4 b2 = *(float4*)&Bs[k + 2][c0];
        float4 b3 = *(float4*)&Bs[k + 3][c0];
#pragma unroll
        for (int i = 0; i < 4; ++i) {
            float4 av = *(float4*)&As[r0 + i][k];
            acc[i][0] = fmaf(av.x, b0.x, fmaf(av.y, b1.x, fmaf(av.z, b2.x, fmaf(av.w, b3.x, acc[i][0]))));
            acc[i][1] = fmaf(av.x, b0.y, fmaf(av.y, b1.y, fmaf(av.z, b2.y, fmaf(av.w, b3.y, acc[i][1]))));
            acc[i][2] = fmaf(av.x, b0.z, fmaf(av.y, b1.z, fmaf(av.z, b2.z, fmaf(av.w, b3.z, acc[i][2]))));
            acc[i][3] = fmaf(av.x, b0.w, fmaf(av.y, b1.w, fmaf(av.z, b2.w, fmaf(av.w, b3.w, acc[i][3]))));
        }
    }
    float4 bv = *(const float4*)&bias[c0];
#pragma unroll
    for (int i = 0; i < 4; ++i) {
        int r = row0 + r0 + i;
        if (r < M) {
            __half2 p0 = __floats2half2_rn(acc[i][0] + bv.x, acc[i][1] + bv.y);
            __half2 p1 = __floats2half2_rn(acc[i][2] + bv.z, acc[i][3] + bv.w);
            uint2 pk;
            pk.x = *(unsigned int*)&p0;
            pk.y = *(unsigned int*)&p1;
            *(uint2*)&Ch[(size_t)r * DIM + c0] = pk;
        }
    }
}

// fused front: blocks [0,SLICES) = slice sort; [SLICES, SLICES+GB) = enc GEMM 0
__global__ __launch_bounds__(256) void k_front(const int* __restrict__ ei,
                                               ushort* __restrict__ usort,
                                               int* __restrict__ ebuf,
                                               int* __restrict__ lpart_u,
                                               int* __restrict__ lpart_v,
                                               const float* __restrict__ A,
                                               const float* __restrict__ W,
                                               const float* __restrict__ bias,
                                               __half* __restrict__ Ch) {
    extern __shared__ char smem[];
    if (blockIdx.x < SLICES)
        lsort_body(smem, ei, usort, ebuf, lpart_u, lpart_v);
    else
        gemm_h_body(smem, blockIdx.x - SLICES, A, W, bias, Ch, NN);
}

// ---------------- fused: [0,BB) u-count -> dis; [BB,2*BB) v-bucket totals.
// Block 0 zeroes colsum.
__global__ __launch_bounds__(256) void k_mid(const ushort* __restrict__ usort,
                                             const int* __restrict__ lpart_u,
                                             const int* __restrict__ lpart_v,
                                             float* __restrict__ dis,
                                             int* __restrict__ tot,
                                             float* __restrict__ colsum) {
    __shared__ int sh[4][64];
    int bid = blockIdx.x;
    if (bid == 0 && threadIdx.x < 64) colsum[threadIdx.x] = 0.f;
    int w = threadIdx.x >> 6, l = threadIdx.x & 63;
    if (bid < BB) {
        int b = bid * 4 + w;
        if (b >= NB) return;
        sh[w][l] = 0;
        __builtin_amdgcn_wave_barrier();
        for (int s = l; s < SLICES; s += 64) {
            const int* row = lpart_u + s * (NB + 1);
            int st = row[b], en = row[b + 1];
            for (int i = st; i < en; ++i)
                atomicAdd(&sh[w][usort[s * ES + i] & 63], 1);
        }
        __builtin_amdgcn_wave_barrier();
        int n = (b << 6) + l;
        if (n < NN) dis[n] = rsqrtf((float)sh[w][l] + 1.0f);
    } else {
        int c = (bid - BB) * 4 + w;
        if (c >= NB) return;
        int sum = 0;
        for (int s = l; s < SLICES; s += 64) {
            const int* row = lpart_v + s * (NB + 1);
            sum += row[c + 1] - row[c];
        }
        for (int off = 32; off; off >>= 1) sum += __shfl_down(sum, off, 64);
        if (l == 0) tot[c] = sum;
    }
}

// ---------------- per-bucket counting sort, LDS-cached; base_v self-computed.
__global__ __launch_bounds__(256) void k_vsort(const int* __restrict__ ebuf,
                                               const int* __restrict__ lpart_v,
                                               const int* __restrict__ tot,
                                               const float* __restrict__ dis,
                                               int* __restrict__ edges,
                                               int* __restrict__ row_ptr) {
    __shared__ int cache[4][VCAP];
    __shared__ int cnt[4][64];
    __shared__ int cur[4][64];
    int w = threadIdx.x >> 6, l = threadIdx.x & 63;
    int b = blockIdx.x * 4 + w;
    if (b >= NB) return;
    int partial = 0;
    for (int c = l; c < b; c += 64) partial += tot[c];
    for (int off = 32; off; off >>= 1) partial += __shfl_down(partial, off, 64);
    int rbase = __shfl(partial, 0, 64);
    int n = tot[b];
    cnt[w][l] = 0;
    __builtin_amdgcn_wave_barrier();
    if (n <= VCAP) {
        int len[4]; int tl = 0;
#pragma unroll
        for (int k = 0; k < 4; ++k) {
            const int* row = lpart_v + (l * 4 + k) * (NB + 1);
            len[k] = row[b + 1] - row[b];
            tl += len[k];
        }
        int inc = tl;
        for (int o = 1; o < 64; o <<= 1) {
            int x = __shfl_up(inc, o, 64);
            if (l >= o) inc += x;
        }
        int pos = inc - tl;
#pragma unroll
        for (int k = 0; k < 4; ++k) {
            int s = l * 4 + k;
            const int* row = lpart_v + s * (NB + 1);
            int st = row[b];
            for (int i = 0; i < len[k]; ++i)
                cache[w][pos++] = ebuf[s * ES + st + i];
        }
        __builtin_amdgcn_wave_barrier();
        for (int i = l; i < n; i += 64)
            atomicAdd(&cnt[w][(cache[w][i] >> 16) & 63], 1);
        __builtin_amdgcn_wave_barrier();
        int c = cnt[w][l];
        int inc2 = c;
        for (int o = 1; o < 64; o <<= 1) {
            int x = __shfl_up(inc2, o, 64);
            if (l >= o) inc2 += x;
        }
        int excl = inc2 - c;
        cur[w][l] = rbase + excl;
        row_ptr[(b << 6) + l] = rbase + excl;
        __builtin_amdgcn_wave_barrier();
        for (int i = l; i < n; i += 64) {
            int rec = cache[w][i];
            int u = rec & 0xFFFF;
            int p2 = atomicAdd(&cur[w][(rec >> 16) & 63], 1);
            ushort dh = __half_as_ushort(__float2half_rn(dis[u]));
            edges[p2] = u | ((int)dh << 16);
        }
    } else {
        for (int s = l; s < SLICES; s += 64) {
            const int* row = lpart_v + s * (NB + 1);
            int st = row[b], en = row[b + 1];
            for (int i = st; i < en; ++i)
                atomicAdd(&cnt[w][(ebuf[s * ES + i] >> 16) & 63], 1);
        }
        __builtin_amdgcn_wave_barrier();
        int c = cnt[w][l];
        int inc2 = c;
        for (int o = 1; o < 64; o <<= 1) {
            int x = __shfl_up(inc2, o, 64);
            if (l >= o) inc2 += x;
        }
        int excl = inc2 - c;
        cur[w][l] = rbase + excl;
        row_ptr[(b << 6) + l] = rbase + excl;
        __builtin_amdgcn_wave_barrier();
        for (int s = l; s < SLICES; s += 64) {
            const int* row = lpart_v + s * (NB + 1);
            int st = row[b], en = row[b + 1];
            for (int i = st; i < en; ++i) {
                int rec = ebuf[s * ES + i];
                int u = rec & 0xFFFF;
                int p2 = atomicAdd(&cur[w][(rec >> 16) & 63], 1);
                ushort dh = __half_as_ushort(__float2half_rn(dis[u]));
                edges[p2] = u | ((int)dh << 16);
            }
        }
    }
}

// ---------------- fused dual GEMM: Zh = half(relu(X@W1+b1)@W2 + b2)
__global__ __launch_bounds__(256) void k_gemm2(const float* __restrict__ X,
                                               const float* __restrict__ W1,
                                               const float* __restrict__ b1,
                                               const float* __restrict__ W2,
                                               const float* __restrict__ b2,
                                               __half* __restrict__ Zh, int M) {
    __shared__ float As[64][68];
    __shared__ float Bs[64][64];
    int t = threadIdx.x;
    int row0 = blockIdx.x * 64;
#pragma unroll
    for (int i = 0; i < 4; ++i) {
        int idx = t + i * 256;
        int r = idx >> 4, c = (idx & 15) << 2;
        float4 val = make_float4(0.f, 0.f, 0.f, 0.f);
        if (row0 + r < M) val = *(const float4*)&X[(size_t)(row0 + r) * DIM + c];
        *(float4*)&As[r][c] = val;
        *(float4*)&Bs[r][c] = *(const float4*)&W1[r * DIM + c];
    }
    __syncthreads();
    int r0 = (t >> 4) * 4;
    int c0 = (t & 15) * 4;
    float acc[4][4] = {};
#pragma unroll
    for (int k = 0; k < 64; k += 4) {
        float4 v0 = *(float4*)&Bs[k + 0][c0];
        float4 v1 = *(float4*)&Bs[k + 1][c0];
        float4 v2 = *(float4*)&Bs[k + 2][c0];
        float4 v3 = *(float4*)&Bs[k + 3][c0];
#pragma unroll
        for (int i = 0; i < 4; ++i) {
            float4 av = *(float4*)&As[r0 + i][k];
            acc[i][0] = fmaf(av.x, v0.x, fmaf(av.y, v1.x, fmaf(av.z, v2.x, fmaf(av.w, v3.x, acc[i][0]))));
            acc[i][1] = fmaf(av.x, v0.y, fmaf(av.y, v1.y, fmaf(av.z, v2.y, fmaf(av.w, v3.y, acc[i][1]))));
            acc[i][2] = fmaf(av.x, v0.z, fmaf(av.y, v1.z, fmaf(av.z, v2.z, fmaf(av.w, v3.z, acc[i][2]))));
            acc[i][3] = fmaf(av.x, v0.w, fmaf(av.y, v1.w, fmaf(av.z, v2.w, fmaf(av.w, v3.w, acc[i][3]))));
        }
    }
    float4 bv1 = *(const float4*)&b1[c0];
    __syncthreads();
#pragma unroll
    for (int i = 0; i < 4; ++i) {
        float4 y;
        y.x = fmaxf(acc[i][0] + bv1.x, 0.f);
        y.y = fmaxf(acc[i][1] + bv1.y, 0.f);
        y.z = fmaxf(acc[i][2] + bv1.z, 0.f);
        y.w = fmaxf(acc[i][3] + bv1.w, 0.f);
        *(float4*)&As[r0 + i][c0] = y;
    }
#pragma unroll
    for (int i = 0; i < 4; ++i) {
        int idx = t + i * 256;
        int r = idx >> 4, c = (idx & 15) << 2;
        *(float4*)&Bs[r][c] = *(const float4*)&W2[r * DIM + c];
    }
    __syncthreads();
    float acc2[4][4] = {};
#pragma unroll
    for (int k = 0; k < 64; k += 4) {
        float4 v0 = *(float4*)&Bs[k + 0][c0];
        float4 v1 = *(float4*)&Bs[k + 1][c0];
        float4 v2 = *(float4*)&Bs[k + 2][c0];
        float4 v3 = *(float4*)&Bs[k + 3][c0];
#pragma unroll
        for (int i = 0; i < 4; ++i) {
            float4 av = *(float4*)&As[r0 + i][k];
            acc2[i][0] = fmaf(av.x, v0.x, fmaf(av.y, v1.x, fmaf(av.z, v2.x, fmaf(av.w, v3.x, acc2[i][0]))));
            acc2[i][1] = fmaf(av.x, v0.y, fmaf(av.y, v1.y, fmaf(av.z, v2.y, fmaf(av.w, v3.y, acc2[i][1]))));
            acc2[i][2] = fmaf(av.x, v0.z, fmaf(av.y, v1.z, fmaf(av.z, v2.z, fmaf(av.w, v3.z, acc2[i][2]))));
            acc2[i][3] = fmaf(av.x, v0.w, fmaf(av.y, v1.w, fmaf(av.z, v2.w, fmaf(av.w, v3.w, acc2[i][3]))));
        }
    }
    float4 bv2 = *(const float4*)&b2[c0];
#pragma unroll
    for (int i = 0; i < 4; ++i) {
        int r = row0 + r0 + i;
        if (r < M) {
            __half2 p0 = __floats2half2_rn(acc2[i][0] + bv2.x, acc2[i][1] + bv2.y);
            __half2 p1 = __floats2half2_rn(acc2[i][2] + bv2.z, acc2[i][3] + bv2.w);
            uint2 pk;
            pk.x = *(unsigned int*)&p0;
            pk.y = *(unsigned int*)&p1;
            *(uint2*)&Zh[(size_t)r * DIM + c0] = pk;
        }
    }
}

// ---------------- last GEMM: relu(X@W+b) -> column sums only (no readout tail:
// R15 showed the fused tail blew VGPR to 256 -> 9% occupancy -> 75 us)
__global__ __launch_bounds__(256) void k_gemm_last(const float* __restrict__ A,
                                                   const float* __restrict__ W,
                                                   const float* __restrict__ bias,
                                                   int M, float* __restrict__ colsum) {
    __shared__ float As[64][68];
    __shared__ float Bs[64][64];
    int t = threadIdx.x;
    int row0 = blockIdx.x * 64;
#pragma unroll
    for (int i = 0; i < 4; ++i) {
        int idx = t + i * 256;
        int r = idx >> 4, c = (idx & 15) << 2;
        float4 val = make_float4(0.f, 0.f, 0.f, 0.f);
        if (row0 + r < M) val = *(const float4*)&A[(size_t)(row0 + r) * DIM + c];
        *(float4*)&As[r][c] = val;
        *(float4*)&Bs[r][c] = *(const float4*)&W[r * DIM + c];
    }
    __syncthreads();
    int r0 = (t >> 4) * 4;
    int c0 = (t & 15) * 4;
    float acc[4][4] = {};
#pragma unroll
    for (int k = 0; k < 64; k += 4) {
        float4 b0 = *(float4*)&Bs[k + 0][c0];
        float4 b1 = *(float4*)&Bs[k + 1][c0];
        float4 b2 = *(float4*)&Bs[k + 2][c0];
        float4 b3 = *(float4*)&Bs[k + 3][c0];
#pragma unroll
        for (int i = 0; i < 4; ++i) {
            float4 av = *(float4*)&As[r0 + i][k];
            acc[i][0] = fmaf(av.x, b0.x, fmaf(av.y, b1.x, fmaf(av.z, b2.x, fmaf(av.w, b3.x, acc[i][0]))));
            acc[i][1] = fmaf(av.x, b0.y, fmaf(av.y, b1.y, fmaf(av.z, b2.y, fmaf(av.w, b3.y, acc[i][1]))));
            acc[i][2] = fmaf(av.x, b0.z, fmaf(av.y, b1.z, fmaf(av.z, b2.z, fmaf(av.w, b3.z, acc[i][2]))));
            acc[i][3] = fmaf(av.x, b0.w, fmaf(av.y, b1.w, fmaf(av.z, b2.w, fmaf(av.w, b3.w, acc[i][3]))));
        }
    }
    float4 bv = *(const float4*)&bias[c0];
    float csum[4] = {0.f, 0.f, 0.f, 0.f};
#pragma unroll
    for (int i = 0; i < 4; ++i) {
        int r = row0 + r0 + i;
        if (r < M) {
            csum[0] += fmaxf(acc[i][0] + bv.x, 0.f);
            csum[1] += fmaxf(acc[i][1] + bv.y, 0.f);
            csum[2] += fmaxf(acc[i][2] + bv.z, 0.f);
            csum[3] += fmaxf(acc[i][3] + bv.w, 0.f);
        }
    }
    float* red = &As[0][0];
    __syncthreads();
    *(float4*)&red[(t >> 4) * 64 + c0] = make_float4(csum[0], csum[1], csum[2], csum[3]);
    __syncthreads();
    if (t < 64) {
        float s = 0.f;
#pragma unroll
        for (int g = 0; g < 16; ++g) s += red[g * 64 + t];
        atomicAdd(&colsum[t], s);
    }
}

// ---------------- aggregation: wave per node, ALWAYS 8-deep gather pipeline
__global__ __launch_bounds__(256) void k_agg(const uint2* __restrict__ Hq,
                                             const float* __restrict__ dis,
                                             const int* __restrict__ row_ptr,
                                             const int* __restrict__ edges,
                                             float* __restrict__ X) {
    __shared__ int se[4][64];
    int w = threadIdx.x >> 6, l = threadIdx.x & 63;
    int node = (blockIdx.x << 2) + w;
    if (node >= NN) return;
    int start = row_ptr[node];
    int num = row_ptr[node + 1] - start;
    int g = l >> 4;           // edge subgroup 0..3
    int p = l & 15;           // feature quad 0..15
    float4 acc = {0.f, 0.f, 0.f, 0.f};
    for (int base = 0; base < num; base += 64) {
        int lim = min(64, num - base);
        se[w][l] = (l < lim) ? edges[start + base + l] : 0;
        __builtin_amdgcn_wave_barrier();
        int quads = (lim + 3) >> 2;          // 1..16
        for (int j = 0; j < quads; j += 8) {
            int rr[8]; uint2 hh[8];
#pragma unroll
            for (int q = 0; q < 8; ++q) rr[q] = se[w][4 * (j + q) + g];
#pragma unroll
            for (int q = 0; q < 8; ++q) hh[q] = Hq[((rr[q] & 0xFFFF) << 4) + p];
#pragma unroll
            for (int q = 0; q < 8; ++q) {
                float wt = __half2float(__ushort_as_half((ushort)((unsigned)rr[q] >> 16)));
                float2 f0 = __half22float2(*(const __half2*)&hh[q].x);
                float2 f1 = __half22float2(*(const __half2*)&hh[q].y);
                acc.x = fmaf(wt, f0.x, acc.x);
                acc.y = fmaf(wt, f0.y, acc.y);
                acc.z = fmaf(wt, f1.x, acc.z);
                acc.w = fmaf(wt, f1.y, acc.w);
            }
        }
        __builtin_amdgcn_wave_barrier();
    }
#pragma unroll
    for (int m = 16; m < 64; m <<= 1) {
        acc.x += __shfl_xor(acc.x, m, 64);
        acc.y += __shfl_xor(acc.y, m, 64);
        acc.z += __shfl_xor(acc.z, m, 64);
        acc.w += __shfl_xor(acc.w, m, 64);
    }
    if (g == 0) {
        uint2 sv = Hq[(node << 4) + p];
        float2 s0 = __half22float2(*(const __half2*)&sv.x);
        float2 s1 = __half22float2(*(const __half2*)&sv.y);
        float dv = dis[node];
        float4 o;
        o.x = fmaf(dv, acc.x, s0.x);
        o.y = fmaf(dv, acc.y, s0.y);
        o.z = fmaf(dv, acc.z, s1.x);
        o.w = fmaf(dv, acc.w, s1.y);
        *(float4*)&X[((size_t)node << 6) + (p << 2)] = o;
    }
}

// ---------------- readout
__global__ void k_out(const float* __restrict__ colsum, const float* __restrict__ out_w,
                      const float* __restrict__ out_b, float* __restrict__ out) {
    int f = threadIdx.x;
    float v = colsum[f] * (1.0f / (float)NN) * out_w[f];
    for (int off = 32; off; off >>= 1) v += __shfl_down(v, off, 64);
    if (f == 0) out[0] = v + out_b[0];
}

extern "C" void kernel_launch(void* const* d_in, const int* in_sizes, int n_in,
                              void* d_out, int out_size, void* d_ws, size_t ws_size,
                              hipStream_t stream) {
    const float* H  = (const float*)d_in[0];
    const int*   ei = (const int*)d_in[1];
    const float* enc_w[3] = { (const float*)d_in[3], (const float*)d_in[7],  (const float*)d_in[11] };
    const float* enc_b[3] = { (const float*)d_in[4], (const float*)d_in[8],  (const float*)d_in[12] };
    const float* upd_w[3] = { (const float*)d_in[5], (const float*)d_in[9],  (const float*)d_in[13] };
    const float* upd_b[3] = { (const float*)d_in[6], (const float*)d_in[10], (const float*)d_in[14] };
    const float* out_w = (const float*)d_in[15];
    const float* out_b = (const float*)d_in[16];
    float* out = (float*)d_out;

    size_t off = 0;
    auto carve = [&](size_t bytes) {
        void* p = (char*)d_ws + off;
        off = (off + bytes + 255) & ~(size_t)255;
        return p;
    };
    int*    lpart_u = (int*)carve((size_t)SLICES * (NB + 1) * 4);
    int*    lpart_v = (int*)carve((size_t)SLICES * (NB + 1) * 4);
    int*    tot     = (int*)carve((size_t)NB * 4);
    float*  dis     = (float*)carve((size_t)NN * 4);
    ushort* usort   = (ushort*)carve((size_t)SLICES * ES * 2);
    int*    ebuf    = (int*)carve((size_t)SLICES * ES * 4);
    int*    edges   = (int*)carve((size_t)NE * 4);
    int*    row_ptr = (int*)carve((size_t)(NN + 65) * 4);
    __half* Ch      = (__half*)carve((size_t)NN * DIM * 2);
    float*  X       = (float*)carve((size_t)NN * DIM * 4);
    float*  colsum  = (float*)carve(64 * 4);

    const int AB = (NN + 3) / 4;     // 12500
    const uint2* Hq = (const uint2*)Ch;

    // front: slice-sort (256 blocks) overlapped with enc-GEMM-0 (782 blocks)
    k_front<<<SLICES + GB, 256, FRONT_LDS, stream>>>(ei, usort, ebuf, lpart_u, lpart_v,
                                                     H, enc_w[0], enc_b[0], Ch);
    k_mid<<<2 * BB, 256, 0, stream>>>(usort, lpart_u, lpart_v, dis, tot, colsum);
    k_vsort<<<BB, 256, 0, stream>>>(ebuf, lpart_v, tot, dis, edges, row_ptr);

    k_agg<<<AB, 256, 0, stream>>>(Hq, dis, row_ptr, edges, X);
    k_gemm2<<<GB, 256, 0, stream>>>(X, upd_w[0], upd_b[0], enc_w[1], enc_b[1], Ch, NN);
    k_agg<<<AB, 256, 0, stream>>>(Hq, dis, row_ptr, edges, X);
    k_gemm2<<<GB, 256, 0, stream>>>(X, upd_w[1], upd_b[1], enc_w[2], enc_b[2], Ch, NN);
    k_agg<<<AB, 256, 0, stream>>>(Hq, dis, row_ptr, edges, X);
    k_gemm_last<<<GB, 256, 0, stream>>>(X, upd_w[2], upd_b[2], NN, colsum);

    k_out<<<1, 64, 0, stream>>>(colsum, out_w, out_b, out);
}